// Round 7
// baseline (156.105 us; speedup 1.0000x reference)
//
#include <hip/hip_runtime.h>
#include <math.h>

// MultiWindowAttention B=4,L=2048,H=8,E=D=64 fp32; w = 32<<(h&3).
// Round 7: R6 + (a) statically balanced XCD schedule (each gid&7 group owns
// 4 (b,h) pairs, one per window class: 32*(3+3+5+9)=640 tile-units each),
// (b) sVt row stride 74 shorts (37 dwords, odd) -> conflict-free V staging.

#define LL 2048
#define HH 8
#define EE 64
#define DD 64
#define RS (HH * EE)    // 512 floats between consecutive seq positions
#define VLD 74          // sVt row stride in shorts (37 dwords, gcd(37,32)=1)

typedef __attribute__((ext_vector_type(8))) short short8;
typedef __attribute__((ext_vector_type(4))) float floatx4;
typedef __attribute__((ext_vector_type(4))) _Float16 half4;
typedef __attribute__((ext_vector_type(2))) __fp16 fp16x2;   // cvt_pkrtz return type

static __device__ __forceinline__ unsigned f2bf(float f) {
    union { float f; unsigned u; } v; v.f = f;
    return (v.u + 0x7fff + ((v.u >> 16) & 1)) >> 16;   // RNE
}
static __device__ __forceinline__ unsigned pack2(float a, float b) {
    return f2bf(a) | (f2bf(b) << 16);
}
static __device__ __forceinline__ unsigned packh2(float a, float b) {
    union { fp16x2 h; unsigned u; } v;
    v.h = __builtin_amdgcn_cvt_pkrtz(a, b);
    return v.u;
}

__global__ __launch_bounds__(256, 4) void mwa_r7(
    const float* __restrict__ Q,
    const float* __restrict__ K,
    const float* __restrict__ V,
    float* __restrict__ O)
{
    const int tid  = threadIdx.x;
    const int lane = tid & 63;
    const int wv   = tid >> 6;
    const int quad = lane >> 4;
    const int l15  = lane & 15;

    // ---- balanced schedule: group gx (presumed XCD gid&7) owns 4 (b,h) pairs,
    //      one per window class; within group, pair interleaved fastest.
    const int gid = blockIdx.x;
    const int gx  = gid & 7;
    const int s   = gid >> 3;            // 0..127
    const int pr  = s & 3;               // window class 0..3
    const int it  = s >> 2;              // 0..31
    const int b   = gx >> 1;
    const int h   = ((gx & 1) << 2) + pr;
    const int i0  = it << 6;
    const int w   = 32 << (h & 3);

    alignas(16) __shared__ short sK [2][4096];      // K frag-linear, bf16 (8KB each)
    alignas(16) __shared__ short sVt[2][64 * VLD];  // V^T [d][j], f16, padded

    const float* Qb = Q + ((size_t)b * LL * HH + h) * EE;
    const float* Kb = K + ((size_t)b * LL * HH + h) * EE;
    const float* Vb = V + ((size_t)b * LL * HH + h) * DD;
    float*       Ob = O + ((size_t)b * LL * HH + h) * DD;

    // ---- stage Q (bf16, ld=72) into sK region (aliased), grab B-frags ----
    {
        const int row = tid >> 2, c = (tid & 3) << 4;
        const float4* src = (const float4*)(Qb + (size_t)(i0 + row) * RS + c);
        float4 f0 = src[0], f1 = src[1], f2 = src[2], f3 = src[3];
        uint4 u0 = { pack2(f0.x,f0.y), pack2(f0.z,f0.w), pack2(f1.x,f1.y), pack2(f1.z,f1.w) };
        uint4 u1 = { pack2(f2.x,f2.y), pack2(f2.z,f2.w), pack2(f3.x,f3.y), pack2(f3.z,f3.w) };
        uint4* dst = (uint4*)&sK[0][row * 72 + c];     // spans into sK[1]; OK pre-loop
        dst[0] = u0; dst[1] = u1;
    }
    __syncthreads();
    short8 qf0, qf1;
    {
        const short* p = &sK[0][(wv * 16 + l15) * 72 + quad * 8];
        qf0 = *(const short8*)p;
        qf1 = *(const short8*)(p + 32);
    }
    __syncthreads();   // all Q-frag reads done before K staging overwrites

    const int jt_lo = max(0, i0 - w) >> 6;
    const int jt_hi = min(LL - 1, i0 + 63 + w) >> 6;

    // ---- stage first tile into buffer 0 ----
    {
        const int j0 = jt_lo << 6;
        const int row = tid >> 2, c = (tid & 3) << 4;
        const float4* src = (const float4*)(Kb + (size_t)(j0 + row) * RS + c);
        float4 f0 = src[0], f1 = src[1], f2 = src[2], f3 = src[3];
        float vv[16];
#pragma unroll
        for (int rr = 0; rr < 16; ++rr)
            vv[rr] = Vb[(size_t)(j0 + wv * 16 + rr) * RS + lane];

        uint4 u0 = { pack2(f0.x,f0.y), pack2(f0.z,f0.w), pack2(f1.x,f1.y), pack2(f1.z,f1.w) };
        uint4 u1 = { pack2(f2.x,f2.y), pack2(f2.z,f2.w), pack2(f3.x,f3.y), pack2(f3.z,f3.w) };
        const int jtw = row >> 4, l15w = row & 15, ks = c >> 5, q0 = (c >> 3) & 3;
        *(uint4*)&sK[0][(((jtw * 2 + ks) * 4 + q0    ) * 16 + l15w) * 8] = u0;
        *(uint4*)&sK[0][(((jtw * 2 + ks) * 4 + q0 + 1) * 16 + l15w) * 8] = u1;

        unsigned* dv = (unsigned*)&sVt[0][0];
#pragma unroll
        for (int rr = 0; rr < 8; ++rr)
            dv[lane * (VLD / 2) + wv * 8 + rr] = packh2(vv[2 * rr], vv[2 * rr + 1]);
    }
    __syncthreads();

    floatx4 acc[4] = {};
    float lsum = 0.f;
    const float scale = 0.125f;
    const int iq = i0 + wv * 16 + l15;   // this lane's query row (q = l15)

    for (int jt = jt_lo; jt <= jt_hi; ++jt) {
        const int cur = (jt - jt_lo) & 1;
        const int nxt = cur ^ 1;
        const bool more = jt < jt_hi;
        const int j0 = jt << 6;

        // ---- prefetch next tile into registers ----
        float4 kf0, kf1, kf2, kf3;
        float vv[16];
        const int rowp = tid >> 2, cp = (tid & 3) << 4;
        if (more) {
            const int jn = (jt + 1) << 6;
            const float4* src = (const float4*)(Kb + (size_t)(jn + rowp) * RS + cp);
            kf0 = src[0]; kf1 = src[1]; kf2 = src[2]; kf3 = src[3];
#pragma unroll
            for (int rr = 0; rr < 16; ++rr)
                vv[rr] = Vb[(size_t)(jn + wv * 16 + rr) * RS + lane];
        }

        // ---- S^T = K.Q^T, then exp -> P^T (stays in registers) ----
        const bool full = ((i0 + 63 - j0) <= w) && ((j0 + 63 - i0) <= w);
        half4 pf[4];
#pragma unroll
        for (int t4 = 0; t4 < 4; ++t4) {
            const short* kp = &sK[cur][1024 * t4 + 128 * quad + 8 * l15];
            short8 k0 = *(const short8*)kp;
            short8 k1 = *(const short8*)(kp + 512);
            floatx4 st = {};
            st = __builtin_amdgcn_mfma_f32_16x16x32_bf16(k0, qf0, st, 0, 0, 0);
            st = __builtin_amdgcn_mfma_f32_16x16x32_bf16(k1, qf1, st, 0, 0, 0);

            float p[4];
            const int jb = j0 + t4 * 16 + quad * 4;
#pragma unroll
            for (int r = 0; r < 4; ++r) {
                float x = st[r] * scale;
                if (!full) {
                    const int di = iq - (jb + r);
                    x = (di <= w && di >= -w) ? x : -INFINITY;
                }
                p[r] = __expf(x);
                lsum += p[r];
            }
            union { half4 v; unsigned u[2]; } pu;
            pu.u[0] = packh2(p[0], p[1]);
            pu.u[1] = packh2(p[2], p[3]);
            pf[t4] = pu.v;
        }

        // ---- O += P.V  (16x16x16 f16; A = P from regs, B = V^T from LDS) ----
#pragma unroll
        for (int nt = 0; nt < 4; ++nt) {
            const short* vbase = &sVt[cur][(nt * 16 + l15) * VLD];
#pragma unroll
            for (int t4 = 0; t4 < 4; ++t4) {
                half4 vf = *(const half4*)(vbase + t4 * 16 + quad * 4);
                acc[nt] = __builtin_amdgcn_mfma_f32_16x16x16f16(pf[t4], vf, acc[nt], 0, 0, 0);
            }
        }

        // ---- write next tile to LDS ----
        if (more) {
            uint4 u0 = { pack2(kf0.x,kf0.y), pack2(kf0.z,kf0.w), pack2(kf1.x,kf1.y), pack2(kf1.z,kf1.w) };
            uint4 u1 = { pack2(kf2.x,kf2.y), pack2(kf2.z,kf2.w), pack2(kf3.x,kf3.y), pack2(kf3.z,kf3.w) };
            const int jtw = rowp >> 4, l15w = rowp & 15, ks = cp >> 5, q0 = (cp >> 3) & 3;
            *(uint4*)&sK[nxt][(((jtw * 2 + ks) * 4 + q0    ) * 16 + l15w) * 8] = u0;
            *(uint4*)&sK[nxt][(((jtw * 2 + ks) * 4 + q0 + 1) * 16 + l15w) * 8] = u1;
            unsigned* dv = (unsigned*)&sVt[nxt][0];
#pragma unroll
            for (int rr = 0; rr < 8; ++rr)
                dv[lane * (VLD / 2) + wv * 8 + rr] = packh2(vv[2 * rr], vv[2 * rr + 1]);
        }
        __syncthreads();
    }

    // ---- epilogue: finish l, normalize, store ----
    lsum += __shfl_xor(lsum, 16, 64);
    lsum += __shfl_xor(lsum, 32, 64);
    float rinv[4];
#pragma unroll
    for (int r = 0; r < 4; ++r) {
        const float lr = __shfl(lsum, quad * 4 + r, 64);
        rinv[r] = 1.0f / lr;
    }
#pragma unroll
    for (int nt = 0; nt < 4; ++nt) {
#pragma unroll
        for (int r = 0; r < 4; ++r) {
            Ob[(size_t)(i0 + wv * 16 + quad * 4 + r) * RS + nt * 16 + l15]
                = acc[nt][r] * rinv[r];
        }
    }
}

extern "C" void kernel_launch(void* const* d_in, const int* in_sizes, int n_in,
                              void* d_out, int out_size, void* d_ws, size_t ws_size,
                              hipStream_t stream)
{
    const float* Q = (const float*)d_in[0];
    const float* K = (const float*)d_in[1];
    const float* V = (const float*)d_in[2];
    float* O = (float*)d_out;

    dim3 grid(4 * HH * (LL / 64)), block(256);   // 1024 blocks
    hipLaunchKernelGGL(mwa_r7, grid, block, 0, stream, Q, K, V, O);
}

// Round 8
// 131.828 us; speedup vs baseline: 1.1842x; 1.1842x over previous
//
#include <hip/hip_runtime.h>
#include <hip/hip_bf16.h>
#include <math.h>

// MultiWindowAttention B=4,L=2048,H=8,E=D=64 fp32; w = 32<<(h&3).
// Round 8: no-LDS, no-barrier flash kernel. All MFMA fragments loaded
// directly from global into registers (L1/L2 serve cross-wave reuse):
//   S^T = K.Q^T  (mfma_f32_16x16x32_bf16): A=K rows, B=Q^T rows - direct.
//   PV  = P.V    (mfma_f32_16x16x16f16):  A=P (regs), B=V[j][d] - direct,
//                                          no transpose needed by layout.
// Schedule: gx=gid&7 group owns 4 (b,h) pairs (one per window class) for
// L2 locality; class pr=(it+k)&3 de-aliased so each CU hosts all 4 classes.

#define LL 2048
#define HH 8
#define EE 64
#define DD 64
#define RS (HH * EE)    // 512 floats between consecutive seq positions

typedef __attribute__((ext_vector_type(8))) short short8;
typedef __attribute__((ext_vector_type(4))) float floatx4;
typedef __attribute__((ext_vector_type(4))) _Float16 half4;
typedef __attribute__((ext_vector_type(2))) __fp16 fp16x2;

static __device__ __forceinline__ unsigned packh2(float a, float b) {
    union { fp16x2 h; unsigned u; } v;
    v.h = __builtin_amdgcn_cvt_pkrtz(a, b);
    return v.u;
}
static __device__ __forceinline__ unsigned packbf2(float a, float b) {
    union { __hip_bfloat162 h; unsigned u; } v;
    v.h = __float22bfloat162_rn(make_float2(a, b));   // v_cvt_pk_bf16_f32
    return v.u;
}
// Load 8 consecutive fp32 -> short8 of bf16 (one MFMA A/B half-fragment).
static __device__ __forceinline__ short8 ldbf8(const float* p) {
    float4 a = *(const float4*)p;
    float4 b = *(const float4*)(p + 4);
    union { short8 s; unsigned u[4]; } f;
    f.u[0] = packbf2(a.x, a.y); f.u[1] = packbf2(a.z, a.w);
    f.u[2] = packbf2(b.x, b.y); f.u[3] = packbf2(b.z, b.w);
    return f.s;
}

__global__ __launch_bounds__(256, 4) void mwa_r8(
    const float* __restrict__ Q,
    const float* __restrict__ K,
    const float* __restrict__ V,
    float* __restrict__ O)
{
    const int tid  = threadIdx.x;
    const int lane = tid & 63;
    const int wv   = tid >> 6;
    const int quad = lane >> 4;
    const int l15  = lane & 15;

    // ---- schedule: XCD-locality grouping + CU-de-aliased window classes ----
    const int gid = blockIdx.x;
    const int gx  = gid & 7;             // presumed XCD
    const int s   = gid >> 3;            // 0..127
    const int it  = s & 31;
    const int k4  = s >> 5;              // 0..3
    const int pr  = (it + k4) & 3;       // window class: de-aliased vs CU assignment
    const int b   = gx >> 1;
    const int h   = ((gx & 1) << 2) + pr;
    const int i0  = it << 6;
    const int w   = 32 << (h & 3);

    const float* Qb = Q + ((size_t)b * LL * HH + h) * EE;
    const float* Kb = K + ((size_t)b * LL * HH + h) * EE;
    const float* Vb = V + ((size_t)b * LL * HH + h) * DD;
    float*       Ob = O + ((size_t)b * LL * HH + h) * DD;

    // ---- Q^T B-frags, direct from global (once) ----
    // B[k=e][n=q]: lane (n=l15 -> query i0+wv*16+l15, k = quad*8 + t [+32])
    const float* qrow = Qb + (size_t)(i0 + wv * 16 + l15) * RS + quad * 8;
    const short8 qf0 = ldbf8(qrow);
    const short8 qf1 = ldbf8(qrow + 32);

    const int jt_lo = max(0, i0 - w) >> 6;
    const int jt_hi = min(LL - 1, i0 + 63 + w) >> 6;

    floatx4 acc[4] = {};
    float lsum = 0.f;
    const float scale = 0.125f;
    const int iq = i0 + wv * 16 + l15;   // this lane's query row (q = l15)

    for (int jt = jt_lo; jt <= jt_hi; ++jt) {
        const int j0 = jt << 6;
        const bool full = ((i0 + 63 - j0) <= w) && ((j0 + 63 - i0) <= w);

        // ---- S^T = K.Q^T; A = K rows direct from global ----
        // A[m=key][k=e]: lane (m = l15 -> key j0+t4*16+l15, k = quad*8+t [+32])
        half4 pf[4];
#pragma unroll
        for (int t4 = 0; t4 < 4; ++t4) {
            const float* krow = Kb + (size_t)(j0 + t4 * 16 + l15) * RS + quad * 8;
            short8 k0 = ldbf8(krow);
            short8 k1 = ldbf8(krow + 32);
            floatx4 st = {};
            st = __builtin_amdgcn_mfma_f32_16x16x32_bf16(k0, qf0, st, 0, 0, 0);
            st = __builtin_amdgcn_mfma_f32_16x16x32_bf16(k1, qf1, st, 0, 0, 0);

            float p[4];
            const int jb = j0 + t4 * 16 + quad * 4;
#pragma unroll
            for (int r = 0; r < 4; ++r) {
                float x = st[r] * scale;
                if (!full) {
                    const int di = iq - (jb + r);
                    x = (di <= w && di >= -w) ? x : -INFINITY;
                }
                p[r] = __expf(x);
                lsum += p[r];
            }
            union { half4 v; unsigned u[2]; } pu;
            pu.u[0] = packh2(p[0], p[1]);
            pu.u[1] = packh2(p[2], p[3]);
            pf[t4] = pu.v;
        }

        // ---- O += P.V ; B = V[j][d] direct from global (no transpose) ----
        // B[k=j][n=d]: lane (n = l15 -> d = nt*16+l15, k = quad*4 + t)
#pragma unroll
        for (int nt = 0; nt < 4; ++nt) {
            const float* vcol = Vb + nt * 16 + l15;
#pragma unroll
            for (int t4 = 0; t4 < 4; ++t4) {
                const size_t jb = (size_t)(j0 + t4 * 16 + quad * 4) * RS;
                float v0 = vcol[jb];
                float v1 = vcol[jb + RS];
                float v2 = vcol[jb + 2 * RS];
                float v3 = vcol[jb + 3 * RS];
                union { half4 v; unsigned u[2]; } vu;
                vu.u[0] = packh2(v0, v1);
                vu.u[1] = packh2(v2, v3);
                acc[nt] = __builtin_amdgcn_mfma_f32_16x16x16f16(pf[t4], vu.v, acc[nt], 0, 0, 0);
            }
        }
    }

    // ---- epilogue: reduce l across quads, normalize, store ----
    lsum += __shfl_xor(lsum, 16, 64);
    lsum += __shfl_xor(lsum, 32, 64);
    float rinv[4];
#pragma unroll
    for (int r = 0; r < 4; ++r) {
        const float lr = __shfl(lsum, quad * 4 + r, 64);
        rinv[r] = 1.0f / lr;
    }
#pragma unroll
    for (int nt = 0; nt < 4; ++nt) {
#pragma unroll
        for (int r = 0; r < 4; ++r) {
            Ob[(size_t)(i0 + wv * 16 + quad * 4 + r) * RS + nt * 16 + l15]
                = acc[nt][r] * rinv[r];
        }
    }
}

extern "C" void kernel_launch(void* const* d_in, const int* in_sizes, int n_in,
                              void* d_out, int out_size, void* d_ws, size_t ws_size,
                              hipStream_t stream)
{
    const float* Q = (const float*)d_in[0];
    const float* K = (const float*)d_in[1];
    const float* V = (const float*)d_in[2];
    float* O = (float*)d_out;

    dim3 grid(4 * HH * (LL / 64)), block(256);   // 1024 blocks
    hipLaunchKernelGGL(mwa_r8, grid, block, 0, stream, Q, K, V, O);
}